// Round 12
// baseline (109.849 us; speedup 1.0000x reference)
//
#include <hip/hip_runtime.h>

#define NHEAD 16
#define DHEAD 64
#define SEQ 2048
#define DMODEL 1024
#define BATCH 2
#define QSCALE 0.1803368801111204f  // 0.125 * log2(e): softmax runs in exp2 domain

typedef __bf16 bf16x8 __attribute__((ext_vector_type(8)));
typedef float f32x4 __attribute__((ext_vector_type(4)));
typedef float f32x16 __attribute__((ext_vector_type(16)));
typedef unsigned int u32x4 __attribute__((ext_vector_type(4)));

__device__ inline unsigned short f2bf(float f) {
  unsigned int u = __builtin_bit_cast(unsigned int, f);
  u = (u + 0x7FFFu + ((u >> 16) & 1u)) >> 16;
  return (unsigned short)u;
}

__device__ inline unsigned int cvtpk_bf16(float lo, float hi) {
  unsigned int r;
  asm("v_cvt_pk_bf16_f32 %0, %1, %2" : "=v"(r) : "v"(lo), "v"(hi));
  return r;
}

__device__ inline void pl32swap(unsigned int& a, unsigned int& b) {
  asm volatile("v_permlane32_swap_b32 %0, %1" : "+v"(a), "+v"(b));
}

// ---------------- convert x to bf16, A-FRAGMENT-MAJOR ----------------
// Af[R(64)][kt(32)][i(4)][lane(64)][e(8)]: lane = ((k>>3)&3)*16 + (n&15), e = k&7, i = (n>>4)&3
__global__ __launch_bounds__(256) void k_conv_x(const float* __restrict__ x,
                                                unsigned short* __restrict__ Af) {
  int blk = blockIdx.x;           // 2048: R = blk>>5, kt = blk&31
  int R = blk >> 5, kt = blk & 31;
  int t = threadIdx.x;
  int i = t >> 6, lane = t & 63;
  int n = R * 64 + i * 16 + (lane & 15);
  int k = kt * 32 + (lane >> 4) * 8;
  const float* xp = x + (size_t)n * DMODEL + k;
  float4 v0 = *(const float4*)xp;
  float4 v1 = *(const float4*)(xp + 4);
  ushort4 lo, hi;
  lo.x = f2bf(v0.x); lo.y = f2bf(v0.y); lo.z = f2bf(v0.z); lo.w = f2bf(v0.w);
  hi.x = f2bf(v1.x); hi.y = f2bf(v1.y); hi.z = f2bf(v1.z); hi.w = f2bf(v1.w);
  size_t base = ((size_t)((R * 32 + kt) * 4 + i) * 64 + lane) * 8;
  *(ushort4*)&Af[base] = lo;
  *(ushort4*)&Af[base + 4] = hi;
}

// ---------------- Wq/Wk/Wv/Wo to B-FRAGMENT-MAJOR bf16 ----------------
// Wf[cb(16)][kt(32)][j(4)][lane(64)][e(8)]: element = src[k][c], lane = ((k>>3)&3)*16 + (c&15)
__global__ __launch_bounds__(256) void k_trans_wf(const float* __restrict__ Wq, const float* __restrict__ Wk,
                                                  const float* __restrict__ Wv, const float* __restrict__ Wo,
                                                  unsigned short* __restrict__ Wqf, unsigned short* __restrict__ Wkf,
                                                  unsigned short* __restrict__ Wvf, unsigned short* __restrict__ Wof) {
  __shared__ float ts[32][65];
  int mat = blockIdx.z;
  const float* src = (mat == 0) ? Wq : (mat == 1) ? Wk : (mat == 2) ? Wv : Wo;
  unsigned short* dst = (mat == 0) ? Wqf : (mat == 1) ? Wkf : (mat == 2) ? Wvf : Wof;
  int cb = blockIdx.x, kt = blockIdx.y;
  int t = threadIdx.x;
  int row = t >> 3, seg = t & 7;
  const float* sp = src + (size_t)(kt * 32 + row) * DMODEL + cb * 64 + seg * 8;
  float4 u0 = *(const float4*)sp;
  float4 u1 = *(const float4*)(sp + 4);
  ts[row][seg * 8 + 0] = u0.x; ts[row][seg * 8 + 1] = u0.y;
  ts[row][seg * 8 + 2] = u0.z; ts[row][seg * 8 + 3] = u0.w;
  ts[row][seg * 8 + 4] = u1.x; ts[row][seg * 8 + 5] = u1.y;
  ts[row][seg * 8 + 6] = u1.z; ts[row][seg * 8 + 7] = u1.w;
  __syncthreads();
  int j = t >> 6, lane = t & 63;
  int c_l = j * 16 + (lane & 15);
  int kb = (lane >> 4) * 8;
  ushort4 lo, hi;
  lo.x = f2bf(ts[kb + 0][c_l]); lo.y = f2bf(ts[kb + 1][c_l]);
  lo.z = f2bf(ts[kb + 2][c_l]); lo.w = f2bf(ts[kb + 3][c_l]);
  hi.x = f2bf(ts[kb + 4][c_l]); hi.y = f2bf(ts[kb + 5][c_l]);
  hi.z = f2bf(ts[kb + 6][c_l]); hi.w = f2bf(ts[kb + 7][c_l]);
  size_t base = ((size_t)((cb * 32 + kt) * 4 + j) * 64 + lane) * 8;
  *(ushort4*)&dst[base] = lo;
  *(ushort4*)&dst[base + 4] = hi;
}

// ---------------- fused QKV projection: barrier-free, 64x128/wave, 2-wave B-sharing blocks ----
// Grid 768 x 128thr: waves (2p, 2p+1) share the SAME B cols -> trailing wave hits L1.
__global__ __launch_bounds__(128, 2) void k_gemm_qkv(const unsigned short* __restrict__ Af,
                                                     const unsigned short* __restrict__ Wqf,
                                                     const unsigned short* __restrict__ Wkf,
                                                     const unsigned short* __restrict__ Wvf,
                                                     unsigned short* __restrict__ Qf,
                                                     unsigned short* __restrict__ Kf,
                                                     unsigned short* __restrict__ Vf) {
  int id = blockIdx.x;            // 768
  int xcd = id & 7, lid = id >> 3;          // 96 per XCD
  int rq = lid / 12, cw = lid % 12;         // cw fastest: same-XCD neighbors share A pair
  int rho = (xcd >> 1) * 8 + rq;            // 0..31 row-pair
  int wv = threadIdx.x >> 6;
  int R = rho * 2 + wv;                     // 0..63 (64-row tile per wave)
  int ct = (xcd & 1) * 12 + cw;             // 0..23 col tile (128 cols over 3 mats)
  int mat = ct >> 3, cb2 = ct & 7;
  const unsigned short* Bf = (mat == 0) ? Wqf : (mat == 1) ? Wkf : Wvf;
  int lane = threadIdx.x & 63;
  const unsigned short* Ap  = Af + (size_t)R * 65536 + lane * 8;
  const unsigned short* Bp0 = Bf + (size_t)(cb2 * 2) * 65536 + lane * 8;
  const unsigned short* Bp1 = Bp0 + 65536;

  f32x4 acc[4][8] = {};
  bf16x8 a0[4], a1[4], b0[8], b1[8];
#pragma unroll
  for (int i = 0; i < 4; i++) a0[i] = *(const bf16x8*)(Ap + i * 512);
#pragma unroll
  for (int j = 0; j < 4; j++) {
    b0[j]     = *(const bf16x8*)(Bp0 + j * 512);
    b0[4 + j] = *(const bf16x8*)(Bp1 + j * 512);
  }
#pragma unroll 1
  for (int kt = 0; kt < 32; kt += 2) {
    {  // prefetch kt+1 into set 1
      const unsigned short* An = Ap + (kt + 1) * 2048;
      const unsigned short* Bn0 = Bp0 + (kt + 1) * 2048;
      const unsigned short* Bn1 = Bp1 + (kt + 1) * 2048;
#pragma unroll
      for (int i = 0; i < 4; i++) a1[i] = *(const bf16x8*)(An + i * 512);
#pragma unroll
      for (int j = 0; j < 4; j++) {
        b1[j]     = *(const bf16x8*)(Bn0 + j * 512);
        b1[4 + j] = *(const bf16x8*)(Bn1 + j * 512);
      }
    }
#pragma unroll
    for (int i = 0; i < 4; i++)
#pragma unroll
      for (int j = 0; j < 8; j++)
        acc[i][j] = __builtin_amdgcn_mfma_f32_16x16x32_bf16(a0[i], b0[j], acc[i][j], 0, 0, 0);
    if (kt + 2 < 32) {  // prefetch kt+2 into set 0
      const unsigned short* An = Ap + (kt + 2) * 2048;
      const unsigned short* Bn0 = Bp0 + (kt + 2) * 2048;
      const unsigned short* Bn1 = Bp1 + (kt + 2) * 2048;
#pragma unroll
      for (int i = 0; i < 4; i++) a0[i] = *(const bf16x8*)(An + i * 512);
#pragma unroll
      for (int j = 0; j < 4; j++) {
        b0[j]     = *(const bf16x8*)(Bn0 + j * 512);
        b0[4 + j] = *(const bf16x8*)(Bn1 + j * 512);
      }
    }
#pragma unroll
    for (int i = 0; i < 4; i++)
#pragma unroll
      for (int j = 0; j < 8; j++)
        acc[i][j] = __builtin_amdgcn_mfma_f32_16x16x32_bf16(a1[i], b1[j], acc[i][j], 0, 0, 0);
  }

  // ---- epilogue: fragment-major Qf/Kf/Vf writes (r9-verified formulas) ----
#pragma unroll
  for (int i = 0; i < 4; i++)
#pragma unroll
    for (int j = 0; j < 8; j++) {
      int n_g = R * 64 + i * 16 + ((lane >> 4) << 2);
      int c = cb2 * 128 + j * 16 + (lane & 15);   // within-matrix col 0..1023
      int b = n_g >> 11, n0 = n_g & 2047;
      int h = c >> 6, d = c & 63;
      int bh = b * NHEAD + h;
      if (mat == 0) {
        size_t base = ((size_t)(bh * 64 + (n0 >> 5)) * 4 + (d >> 4)) * 512 +
                      (size_t)((((d >> 3) & 1) * 32 + (n0 & 31)) * 8 + (d & 7));
#pragma unroll
        for (int r = 0; r < 4; r++) Qf[base + 8 * r] = f2bf(acc[i][j][r] * QSCALE);
      } else if (mat == 1) {
        size_t base = ((size_t)(bh * 32 + (n0 >> 6)) * 8 + ((d >> 4) + 4 * ((n0 >> 5) & 1))) * 512 +
                      (size_t)((((d >> 3) & 1) * 32 + (n0 & 31)) * 8 + (d & 7));
#pragma unroll
        for (int r = 0; r < 4; r++) Kf[base + 8 * r] = f2bf(acc[i][j][r]);
      } else {
        size_t base = ((size_t)(bh * 32 + (n0 >> 6)) * 8 + (((n0 >> 4) & 3) + 4 * (d >> 5))) * 512 +
                      (size_t)((((n0 >> 3) & 1) * 32 + (d & 31)) * 8 + (n0 & 7));
        ushort4 o;
        o.x = f2bf(acc[i][j][0]); o.y = f2bf(acc[i][j][1]);
        o.z = f2bf(acc[i][j][2]); o.w = f2bf(acc[i][j][3]);
        *(ushort4*)&Vf[base] = o;
      }
    }
}

// ---------------- flash attention (causal): r9 body, epilogue writes Obf A-fragment-major ----
__global__ __launch_bounds__(64, 2) void k_attn(const unsigned short* __restrict__ Qf,
                                                const unsigned short* __restrict__ Kf,
                                                const unsigned short* __restrict__ Vf,
                                                unsigned short* __restrict__ Obf) {
  int id = blockIdx.x;
  int xcd = id & 7, m = id >> 3;
  int bhl = m & 3, u = m >> 2;
  int bh = xcd * 4 + bhl;
  int v = (u < 32) ? (63 - u) : (u - 32);
  int nk = (v >> 1) + 1;
  int lane = threadIdx.x;
  int h = lane >> 5, ql = lane & 31;
  int qrow = v * 32 + ql;

  const unsigned short* Qp = Qf + (size_t)bh * 131072 + (size_t)v * 2048;
  const unsigned short* Kp = Kf + (size_t)bh * 131072;
  const unsigned short* Vp = Vf + (size_t)bh * 131072;
  int b = bh >> 4, hh = bh & 15;

  bf16x8 qv[4];
#pragma unroll
  for (int ds = 0; ds < 4; ds++)
    qv[ds] = *(const bf16x8*)&Qp[ds * 512 + lane * 8];

  bf16x8 Kr[8], Vr[8];
#pragma unroll
  for (int jj = 0; jj < 8; jj++) Kr[jj] = *(const bf16x8*)&Kp[jj * 512 + lane * 8];
#pragma unroll
  for (int jj = 0; jj < 8; jj++) Vr[jj] = *(const bf16x8*)&Vp[jj * 512 + lane * 8];

  f32x16 o0 = {}, o1 = {};
  float m_r = -3.0e38f, l_r = 0.0f;

#pragma unroll 1
  for (int kc = 0; kc < nk; ++kc) {
    f32x16 s0 = {}, s1 = {};
#pragma unroll
    for (int ds = 0; ds < 4; ds++) {
      s0 = __builtin_amdgcn_mfma_f32_32x32x16_bf16(Kr[ds], qv[ds], s0, 0, 0, 0);
      s1 = __builtin_amdgcn_mfma_f32_32x32x16_bf16(Kr[4 + ds], qv[ds], s1, 0, 0, 0);
    }
    bool pfn = (kc + 1 < nk);
    size_t nb = (size_t)(kc + 1) * 4096;
    if (pfn) {
#pragma unroll
      for (int jj = 0; jj < 8; jj++) Kr[jj] = *(const bf16x8*)&Kp[nb + jj * 512 + lane * 8];
    }
    int k0 = kc * 64;
    if (kc == nk - 1) {
#pragma unroll
      for (int r = 0; r < 16; r++) {
        int kloc = (r & 3) + 8 * (r >> 2) + 4 * h;
        if (k0 + kloc > qrow) s0[r] = -3.0e38f;
        if (k0 + 32 + kloc > qrow) s1[r] = -3.0e38f;
      }
    }
    float t0[8], t1[8];
#pragma unroll
    for (int r = 0; r < 8; r++) t0[r] = fmaxf(s0[r], s0[r + 8]);
#pragma unroll
    for (int r = 0; r < 8; r++) t1[r] = fmaxf(s1[r], s1[r + 8]);
#pragma unroll
    for (int r = 0; r < 4; r++) t0[r] = fmaxf(fmaxf(t0[r], t0[r + 4]), fmaxf(t1[r], t1[r + 4]));
    float pm = fmaxf(fmaxf(t0[0], t0[1]), fmaxf(t0[2], t0[3]));
    pm = fmaxf(pm, __shfl_xor(pm, 32));
    bool grow = pm > m_r + 8.0f;
    float mnew = grow ? pm : m_r;
    float sf = grow ? __builtin_amdgcn_exp2f(m_r - mnew) : 1.0f;
    m_r = mnew;
    float rsum = 0.0f;
#pragma unroll
    for (int r = 0; r < 16; r++) { s0[r] = __builtin_amdgcn_exp2f(s0[r] - m_r); rsum += s0[r]; }
#pragma unroll
    for (int r = 0; r < 16; r++) { s1[r] = __builtin_amdgcn_exp2f(s1[r] - m_r); rsum += s1[r]; }
    l_r = l_r * sf + rsum;
    if (__ballot(grow)) {
#pragma unroll
      for (int r = 0; r < 16; r++) { o0[r] *= sf; o1[r] *= sf; }
    }
    unsigned int pa0 = cvtpk_bf16(s0[0], s0[1]),   pa1 = cvtpk_bf16(s0[2], s0[3]);
    unsigned int pb0 = cvtpk_bf16(s0[4], s0[5]),   pb1 = cvtpk_bf16(s0[6], s0[7]);
    unsigned int pc0 = cvtpk_bf16(s0[8], s0[9]),   pc1 = cvtpk_bf16(s0[10], s0[11]);
    unsigned int pd0 = cvtpk_bf16(s0[12], s0[13]), pd1 = cvtpk_bf16(s0[14], s0[15]);
    unsigned int pe0 = cvtpk_bf16(s1[0], s1[1]),   pe1 = cvtpk_bf16(s1[2], s1[3]);
    unsigned int pf0 = cvtpk_bf16(s1[4], s1[5]),   pf1 = cvtpk_bf16(s1[6], s1[7]);
    unsigned int pg0 = cvtpk_bf16(s1[8], s1[9]),   pg1 = cvtpk_bf16(s1[10], s1[11]);
    unsigned int ph0 = cvtpk_bf16(s1[12], s1[13]), ph1 = cvtpk_bf16(s1[14], s1[15]);
    pl32swap(pa0, pb0); pl32swap(pa1, pb1);
    pl32swap(pc0, pd0); pl32swap(pc1, pd1);
    pl32swap(pe0, pf0); pl32swap(pe1, pf1);
    pl32swap(pg0, ph0); pl32swap(pg1, ph1);
    bf16x8 pfr[4];
    pfr[0] = __builtin_bit_cast(bf16x8, (u32x4){pa0, pa1, pb0, pb1});
    pfr[1] = __builtin_bit_cast(bf16x8, (u32x4){pc0, pc1, pd0, pd1});
    pfr[2] = __builtin_bit_cast(bf16x8, (u32x4){pe0, pe1, pf0, pf1});
    pfr[3] = __builtin_bit_cast(bf16x8, (u32x4){pg0, pg1, ph0, ph1});
#pragma unroll
    for (int ks = 0; ks < 4; ks++) {
      o0 = __builtin_amdgcn_mfma_f32_32x32x16_bf16(Vr[ks], pfr[ks], o0, 0, 0, 0);
      o1 = __builtin_amdgcn_mfma_f32_32x32x16_bf16(Vr[4 + ks], pfr[ks], o1, 0, 0, 0);
    }
    if (pfn) {
#pragma unroll
      for (int jj = 0; jj < 8; jj++) Vr[jj] = *(const bf16x8*)&Vp[nb + jj * 512 + lane * 8];
    }
  }

  // ---- epilogue: O = O^T / l, written A-FRAGMENT-MAJOR for k_gemm_out ----
  // element (n = b*2048 + v*32 + ql, k = hh*64 + d): R=b*32+(v>>1), kt=2hh(+1 for o1),
  // i=(2v+(ql>>4))&3, lane'=rg*16+(ql&15), e=4h+s  (d = 8rg+4h+s (+32 o1))
  float lt = l_r + __shfl_xor(l_r, 32);
  float rl = 1.0f / lt;
  int Rg = b * 32 + (v >> 1);
  int ii = (v * 2 + (ql >> 4)) & 3;
  size_t base0 = ((size_t)(Rg * 32 + 2 * hh) * 4 + ii) * 512 + (size_t)((ql & 15) * 8 + 4 * h);
  size_t base1 = base0 + 2048;  // kt = 2hh+1 (o1: d+32)
#pragma unroll
  for (int rg = 0; rg < 4; rg++) {
    uint2 w0, w1;
    w0.x = cvtpk_bf16(o0[4 * rg] * rl, o0[4 * rg + 1] * rl);
    w0.y = cvtpk_bf16(o0[4 * rg + 2] * rl, o0[4 * rg + 3] * rl);
    w1.x = cvtpk_bf16(o1[4 * rg] * rl, o1[4 * rg + 1] * rl);
    w1.y = cvtpk_bf16(o1[4 * rg + 2] * rl, o1[4 * rg + 3] * rl);
    *(uint2*)&Obf[base0 + rg * 128] = w0;
    *(uint2*)&Obf[base1 + rg * 128] = w1;
  }
}

// ---------------- output projection: barrier-free fragment streaming, 64x64/wave ----------------
// Grid 1024 = 8 XCD x (8 R-groups x 16 col-tiles); per-XCD A 1MB + B 2MB < L2.
__global__ __launch_bounds__(64, 2) void k_gemm_out(const unsigned short* __restrict__ Obf,
                                                    const unsigned short* __restrict__ Wof,
                                                    float* __restrict__ out) {
  int id = blockIdx.x;            // 1024
  int xcd = id & 7, lid = id >> 3;   // 128 per XCD
  int rg8 = lid >> 4, cb = lid & 15; // cb fastest: same-XCD neighbors share A
  int R = xcd * 8 + rg8;             // 0..63
  int lane = threadIdx.x;
  const unsigned short* Ap = Obf + (size_t)R * 65536 + lane * 8;
  const unsigned short* Bp = Wof + (size_t)cb * 65536 + lane * 8;

  f32x4 acc[4][4] = {};
  bf16x8 a0[4], b0[4], a1[4], b1[4];
#pragma unroll
  for (int i = 0; i < 4; i++) {
    a0[i] = *(const bf16x8*)(Ap + i * 512);
    b0[i] = *(const bf16x8*)(Bp + i * 512);
  }
#pragma unroll 1
  for (int kt = 0; kt < 32; kt += 2) {
    {  // prefetch kt+1 into set 1
      const unsigned short* An = Ap + (kt + 1) * 2048;
      const unsigned short* Bn = Bp + (kt + 1) * 2048;
#pragma unroll
      for (int i = 0; i < 4; i++) {
        a1[i] = *(const bf16x8*)(An + i * 512);
        b1[i] = *(const bf16x8*)(Bn + i * 512);
      }
    }
#pragma unroll
    for (int i = 0; i < 4; i++)
#pragma unroll
      for (int j = 0; j < 4; j++)
        acc[i][j] = __builtin_amdgcn_mfma_f32_16x16x32_bf16(a0[i], b0[j], acc[i][j], 0, 0, 0);
    if (kt + 2 < 32) {  // prefetch kt+2 into set 0
      const unsigned short* An = Ap + (kt + 2) * 2048;
      const unsigned short* Bn = Bp + (kt + 2) * 2048;
#pragma unroll
      for (int i = 0; i < 4; i++) {
        a0[i] = *(const bf16x8*)(An + i * 512);
        b0[i] = *(const bf16x8*)(Bn + i * 512);
      }
    }
#pragma unroll
    for (int i = 0; i < 4; i++)
#pragma unroll
      for (int j = 0; j < 4; j++)
        acc[i][j] = __builtin_amdgcn_mfma_f32_16x16x32_bf16(a1[i], b1[j], acc[i][j], 0, 0, 0);
  }

  // ---- epilogue: fp32 C-write (r9-verified C/D mapping) ----
#pragma unroll
  for (int i = 0; i < 4; i++)
#pragma unroll
    for (int j = 0; j < 4; j++) {
      int n_g = R * 64 + i * 16 + ((lane >> 4) << 2);
      int c = cb * 64 + j * 16 + (lane & 15);
#pragma unroll
      for (int r = 0; r < 4; r++)
        out[(size_t)(n_g + r) * DMODEL + c] = acc[i][j][r];
    }
}

extern "C" void kernel_launch(void* const* d_in, const int* in_sizes, int n_in,
                              void* d_out, int out_size, void* d_ws, size_t ws_size,
                              hipStream_t stream) {
  const float* x  = (const float*)d_in[0];
  const float* Wq = (const float*)d_in[1];
  const float* Wk = (const float*)d_in[2];
  const float* Wv = (const float*)d_in[3];
  const float* Wo = (const float*)d_in[4];
  float* out = (float*)d_out;
  char* ws = (char*)d_ws;
  unsigned short* Af  = (unsigned short*)(ws);
  unsigned short* Wqf = (unsigned short*)(ws + (8ull << 20));
  unsigned short* Wkf = (unsigned short*)(ws + (10ull << 20));
  unsigned short* Wvf = (unsigned short*)(ws + (12ull << 20));
  unsigned short* Wof = (unsigned short*)(ws + (14ull << 20));
  unsigned short* Qf  = (unsigned short*)(ws + (16ull << 20));
  unsigned short* Kf  = (unsigned short*)(ws + (24ull << 20));
  unsigned short* Vf  = (unsigned short*)(ws + (32ull << 20));
  unsigned short* Obf = (unsigned short*)(ws + (40ull << 20));

  k_conv_x<<<dim3(2048), dim3(256), 0, stream>>>(x, Af);
  k_trans_wf<<<dim3(16, 32, 4), dim3(256), 0, stream>>>(Wq, Wk, Wv, Wo, Wqf, Wkf, Wvf, Wof);
  k_gemm_qkv<<<dim3(768), dim3(128), 0, stream>>>(Af, Wqf, Wkf, Wvf, Qf, Kf, Vf);
  k_attn<<<dim3(2048), dim3(64), 0, stream>>>(Qf, Kf, Vf, Obf);
  k_gemm_out<<<dim3(1024), dim3(64), 0, stream>>>(Obf, Wof, out);
}